// Round 1
// baseline (168.452 us; speedup 1.0000x reference)
//
#include <hip/hip_runtime.h>
#include <hip/hip_bf16.h>
#include <type_traits>

// out[b] = X[b] @ (X[b]^T @ X[b]);  B=8, S=4096, D=512, fp32 in/out.
// Pipeline (bf16 MFMA, fp32 accumulate), ws = 268MB observed:
//   k1: Xt[d][s] bf16 -> d_out[0:33.5M) ; Xb16[s][d] bf16 -> ws+4.2M
//   k2: split-K=8 gram partials bf16 -> ws+37.7M (XCD-swizzled, LDS dbuf)
//       (split 8 not 4: 1024 blocks = 4/CU; at split 4 the 512-block grid
//        capped occupancy at 2/CU and exposed the barrier-drain stall)
//   kr: reduce 8 bf16 partials -> bf16 gram -> ws[0:4.2M)
//   k3: out = Xb16 . gram^T (both K-contig, async-LDS dbuf, XCD-swizzled) -> d_out

typedef __attribute__((ext_vector_type(8))) short short8;
typedef __attribute__((ext_vector_type(4))) float floatx4;

#define BM 128
#define BN 128
#define BK 32

#define BATCH 8
#define SEQ 4096
#define DIM 512
#define SPLITK 8

__device__ __forceinline__ void async_copy16(const __hip_bfloat16* g, __hip_bfloat16* l) {
  __builtin_amdgcn_global_load_lds((const __attribute__((address_space(1))) void*)g,
                                   (__attribute__((address_space(3))) void*)l, 16, 0, 0);
}

// ---------------- k1: transpose+cast (Xt) and optional straight cast (Xb16) --
__global__ __launch_bounds__(256) void transpose_cast_kernel(
    const float* __restrict__ X, __hip_bfloat16* __restrict__ Xt,
    __hip_bfloat16* __restrict__ Xb16) {
  __shared__ float tile[64][65];
  const int b = blockIdx.z;
  const int s0 = blockIdx.x * 64;
  const int d0 = blockIdx.y * 64;
  const int tid = threadIdx.x;
  const float* Xb = X + (long)b * SEQ * DIM;
  __hip_bfloat16* Xtb = Xt + (long)b * DIM * SEQ;
  // float4-vectorized tile fill: 4 global loads/thread instead of 16 scalar.
  // LDS writes stay scalar (tile stride 65 keeps both read phases 2-way-free;
  // any float4-alignable stride collapses banks for the stride-8 row reads).
  {
    const int c4 = (tid & 15) * 4;
    const int r0 = tid >> 4;  // 0..15
#pragma unroll
    for (int r = 0; r < 64; r += 16) {
      const float4 v = *(const float4*)&Xb[(long)(s0 + r + r0) * DIM + d0 + c4];
      tile[r + r0][c4 + 0] = v.x;
      tile[r + r0][c4 + 1] = v.y;
      tile[r + r0][c4 + 2] = v.z;
      tile[r + r0][c4 + 3] = v.w;
    }
  }
  __syncthreads();
  // Xt[d][s]: pack 8 consecutive s per 16B store.
#pragma unroll
  for (int it = 0; it < 2; ++it) {
    const int idx = it * 256 + tid;    // 0..511
    const int dl = idx >> 3;           // 0..63
    const int so = (idx & 7) * 8;      // 0,8,..,56
    union { short8 v; __hip_bfloat16 e[8]; } u;
#pragma unroll
    for (int j = 0; j < 8; ++j) u.e[j] = __float2bfloat16(tile[so + j][dl]);
    *(short8*)&Xtb[(long)(d0 + dl) * SEQ + s0 + so] = u.v;
  }
  // Xb16[s][d]: straight cast, pack 8 consecutive d per 16B store.
  if (Xb16 != nullptr) {
    __hip_bfloat16* Xcb = Xb16 + (long)b * SEQ * DIM;
#pragma unroll
    for (int it = 0; it < 2; ++it) {
      const int idx = it * 256 + tid;  // 0..511
      const int sl = idx >> 3;         // 0..63
      const int dc = idx & 7;          // 8-wide d chunk
      union { short8 v; __hip_bfloat16 e[8]; } u;
#pragma unroll
      for (int j = 0; j < 8; ++j) u.e[j] = __float2bfloat16(tile[sl][dc * 8 + j]);
      *(short8*)&Xcb[(long)(s0 + sl) * DIM + d0 + dc * 8] = u.v;
    }
  }
}

// ---------------- GEMM: C = A . Bt^T (Bt stored [N][K], K-contiguous) -------
// Double-buffered LDS: next tile's global_load_lds copies are issued right
// after the barrier that opens compute on the current buffer.
// __launch_bounds__(256,4): force <=128 unified regs/wave -> 4 blocks/CU.
// NSPLIT: split-K factor. AFP32: A fp32 cast-in-staging w/ register prefetch.
// CT: C element type (float or bf16).
// SWZ=1: grid(128,1,B) k3-style: m-slab's 4 n-blocks share an XCD.
// SWZ=2: grid(B*NSPLIT,16,1) k2-style: one (b,split) chunk -> one XCD.
template <int NSPLIT, bool AFP32, int SWZ, typename CT>
__global__ __launch_bounds__(256, 4) void gemm_bt_kernel(
    const float* __restrict__ Af, const __hip_bfloat16* __restrict__ Ab,
    const __hip_bfloat16* __restrict__ Bt, CT* __restrict__ C,
    int K, int lda, int ldb, int ldc, long strideA, long strideB, long strideC) {
  __shared__ __align__(16) __hip_bfloat16 As[2][BM * BK];  // [m][k]
  __shared__ __align__(16) __hip_bfloat16 Bs[2][BN * BK];  // [n][k]

  int bz, m0, n0;
  if constexpr (SWZ == 1) {
    const int lin = blockIdx.x;        // 0..127 per batch
    bz = blockIdx.z;
    const int xcd = lin & 7;
    const int t = lin >> 3;            // 0..15
    n0 = (t & 3) * BN;
    m0 = ((t >> 2) * 8 + xcd) * BM;
  } else if constexpr (SWZ == 2) {
    bz = blockIdx.x;                   // chunk id, fastest dim -> xcd = bz & 7
    const int t = blockIdx.y;          // 0..15 tile
    m0 = (t >> 2) * BM;
    n0 = (t & 3) * BN;
  } else {
    bz = blockIdx.z;
    m0 = blockIdx.y * BM;
    n0 = blockIdx.x * BN;
  }
  const int b = bz / NSPLIT;
  const int split = bz % NSPLIT;
  const int klen = K / NSPLIT;
  const int kb = split * klen;

  const int tid = threadIdx.x;
  const int w = tid >> 6;
  const int lane = tid & 63;
  const int r16 = lane & 15;
  const int kg = lane >> 4;
  const int wr = w >> 1;
  const int wc = w & 1;

  const float* Afb = AFP32 ? Af + b * strideA : nullptr;
  const __hip_bfloat16* Abb = AFP32 ? nullptr : Ab + b * strideA;
  const __hip_bfloat16* Btb = Bt + b * strideB;
  CT* Cb = C + (long)bz * strideC;

  const floatx4 vzero = {0.f, 0.f, 0.f, 0.f};
  floatx4 acc[4][4];
#pragma unroll
  for (int i = 0; i < 4; ++i)
#pragma unroll
    for (int j = 0; j < 4; ++j) acc[i][j] = vzero;

  const int arow = tid >> 1;
  const int ahalf = tid & 1;
  float f[16];

  auto stageB = [&](int buf, int k0) {
#pragma unroll
    for (int q = 0; q < 2; ++q) {
      const __hip_bfloat16* gb =
          Btb + (long)(n0 + w * 32 + q * 16 + (lane >> 2)) * ldb + k0 + (lane & 3) * 8;
      async_copy16(gb, &Bs[buf][(w * 32 + q * 16) * BK]);
    }
  };
  auto stageA = [&](int buf, int k0) {
#pragma unroll
    for (int q = 0; q < 2; ++q) {
      const __hip_bfloat16* ga =
          Abb + (long)(m0 + w * 32 + q * 16 + (lane >> 2)) * lda + k0 + (lane & 3) * 8;
      async_copy16(ga, &As[buf][(w * 32 + q * 16) * BK]);
    }
  };
  auto loadF = [&](int k0) {
    const float* ar = Afb + (long)(m0 + arow) * lda + k0 + ahalf * 16;
    *(float4*)(f + 0)  = *(const float4*)(ar + 0);
    *(float4*)(f + 4)  = *(const float4*)(ar + 4);
    *(float4*)(f + 8)  = *(const float4*)(ar + 8);
    *(float4*)(f + 12) = *(const float4*)(ar + 12);
  };
  auto writeF = [&](int buf) {
    union { short8 v[2]; __hip_bfloat16 e[16]; } u;
#pragma unroll
    for (int t = 0; t < 16; ++t) u.e[t] = __float2bfloat16(f[t]);
    short8* dst = (short8*)&As[buf][arow * BK + ahalf * 16];
    dst[0] = u.v[0];
    dst[1] = u.v[1];
  };

  const int nIter = klen / BK;
  // prologue: fill buffer 0
  if constexpr (AFP32) {
    loadF(kb);
    writeF(0);
    loadF(kb + BK);  // prefetch tile 1 into registers
  } else {
    stageA(0, kb);
  }
  stageB(0, kb);

  for (int t = 0; t < nIter; ++t) {
    const int cur = t & 1;
    __syncthreads();  // drains vmcnt/lgkm: buffer `cur` is ready
    // issue next tile into the other buffer; it stays in flight during compute
    if (t + 1 < nIter) {
      if constexpr (AFP32) {
        writeF(cur ^ 1);
        if (t + 2 < nIter) loadF(kb + (t + 2) * BK);
      } else {
        stageA(cur ^ 1, kb + (t + 1) * BK);
      }
      stageB(cur ^ 1, kb + (t + 1) * BK);
    }

    short8 a[4], bfrag[4];
#pragma unroll
    for (int i = 0; i < 4; ++i)
      a[i] = *(const short8*)&As[cur][(wr * 64 + i * 16 + r16) * BK + kg * 8];
#pragma unroll
    for (int j = 0; j < 4; ++j)
      bfrag[j] = *(const short8*)&Bs[cur][(wc * 64 + j * 16 + r16) * BK + kg * 8];
#pragma unroll
    for (int i = 0; i < 4; ++i)
#pragma unroll
      for (int j = 0; j < 4; ++j)
        acc[i][j] = __builtin_amdgcn_mfma_f32_16x16x32_bf16(a[i], bfrag[j], acc[i][j], 0, 0, 0);
  }

  // epilogue: row = kg*4 + r, col = r16 (m89-verified C/D map)
#pragma unroll
  for (int i = 0; i < 4; ++i) {
    const int row_base = m0 + wr * 64 + i * 16 + kg * 4;
#pragma unroll
    for (int j = 0; j < 4; ++j) {
      const int col = n0 + wc * 64 + j * 16 + r16;
#pragma unroll
      for (int r = 0; r < 4; ++r) {
        const float v = acc[i][j][r];
        if constexpr (std::is_same<CT, float>::value)
          Cb[(long)(row_base + r) * ldc + col] = v;
        else
          Cb[(long)(row_base + r) * ldc + col] = __float2bfloat16(v);
      }
    }
  }
}

// ---------------- kr: reduce NSPLIT bf16 partials -> bf16 gram --------------
template <int NSPLIT>
__global__ __launch_bounds__(256) void reduce_cast_kernel(
    const __hip_bfloat16* __restrict__ P, __hip_bfloat16* __restrict__ G) {
  const int DD8 = DIM * DIM / 8;  // 16B-vector count per [b][split]
  const long idx = (long)blockIdx.x * 256 + threadIdx.x;  // 0 .. B*DD8
  const int b = (int)(idx / DD8);
  const int e = (int)(idx % DD8);
  const __hip_bfloat16* base = P + (long)(b * NSPLIT) * DIM * DIM + (long)e * 8;
  float s[8] = {0.f, 0.f, 0.f, 0.f, 0.f, 0.f, 0.f, 0.f};
#pragma unroll
  for (int p = 0; p < NSPLIT; ++p) {
    union { short8 v; __hip_bfloat16 e8[8]; } u;
    u.v = *(const short8*)(base + (long)p * DIM * DIM);
#pragma unroll
    for (int j = 0; j < 8; ++j) s[j] += __bfloat162float(u.e8[j]);
  }
  union { short8 v; __hip_bfloat16 e8[8]; } o;
#pragma unroll
  for (int j = 0; j < 8; ++j) o.e8[j] = __float2bfloat16(s[j]);
  *(short8*)&G[(long)idx * 8] = o.v;
}

// ---------------- host launch ----------------------------------------------
extern "C" void kernel_launch(void* const* d_in, const int* in_sizes, int n_in,
                              void* d_out, int out_size, void* d_ws, size_t ws_size,
                              hipStream_t stream) {
  const float* X = (const float*)d_in[0];
  float* out = (float*)d_out;
  const long xtBytes = (long)BATCH * DIM * SEQ * 2;               // 33.5 MB
  const long gramBytes = (long)BATCH * DIM * DIM * 2;             // 4.2 MB
  const long partBytes = (long)BATCH * SPLITK * DIM * DIM * 2;    // 33.5 MB (bf16)
  __hip_bfloat16* Xt = (__hip_bfloat16*)d_out;
  __hip_bfloat16* gram = (__hip_bfloat16*)d_ws;

  const bool bigWs = ws_size >= (size_t)(gramBytes + xtBytes + partBytes);
  const bool midWs = ws_size >= (size_t)(gramBytes + xtBytes);
  __hip_bfloat16* Xb16 = midWs ? (__hip_bfloat16*)((char*)d_ws + gramBytes) : nullptr;

  // k1: Xt[b][d][s] (+ Xb16[b][s][d] if ws fits)
  transpose_cast_kernel<<<dim3(SEQ / 64, DIM / 64, BATCH), 256, 0, stream>>>(X, Xt, Xb16);

  // k2: split-8 gram partials (bf16), XCD-swizzled, double-buffered.
  // grid = 64 chunks x 16 tiles = 1024 blocks -> 4 blocks/CU (split 4 gave 2/CU).
  __hip_bfloat16* partials = bigWs
      ? (__hip_bfloat16*)((char*)d_ws + gramBytes + xtBytes)
      : (__hip_bfloat16*)((char*)d_out + xtBytes);
  gemm_bt_kernel<SPLITK, false, 2, __hip_bfloat16>
      <<<dim3(BATCH * SPLITK, 16, 1), 256, 0, stream>>>(
          nullptr, Xt, Xt, partials, SEQ, SEQ, SEQ, DIM,
          (long)DIM * SEQ, (long)DIM * SEQ, (long)DIM * DIM);
  reduce_cast_kernel<SPLITK><<<dim3(BATCH * DIM * DIM / 8 / 256), 256, 0, stream>>>(
      partials, gram);

  // k3: out = A . gram^T (M=4096, N=512, K=512), XCD-swizzled, double-buffered
  if (midWs) {
    gemm_bt_kernel<1, false, 1, float><<<dim3(128, 1, BATCH), 256, 0, stream>>>(
        nullptr, Xb16, gram, out, DIM, DIM, DIM, DIM,
        (long)SEQ * DIM, (long)DIM * DIM, (long)SEQ * DIM);
  } else {
    gemm_bt_kernel<1, true, 1, float><<<dim3(128, 1, BATCH), 256, 0, stream>>>(
        X, nullptr, gram, out, DIM, DIM, DIM, DIM,
        (long)SEQ * DIM, (long)DIM * DIM, (long)SEQ * DIM);
  }
}

// Round 2
// 166.752 us; speedup vs baseline: 1.0102x; 1.0102x over previous
//
#include <hip/hip_runtime.h>
#include <hip/hip_bf16.h>
#include <type_traits>

// out[b] = X[b] @ (X[b]^T @ X[b]);  B=8, S=4096, D=512, fp32 in/out.
// Pipeline (bf16 MFMA, fp32 accumulate), ws = 268MB observed:
//   k1: Xt[d][s] bf16 -> d_out[0:33.5M) ; Xb16[s][d] bf16 -> ws+4.2M
//   k2: split-K=8 gram partials bf16 -> ws+37.7M (XCD-swizzled, LDS dbuf)
//       SYMMETRY: gram = Xt.Xt^T is symmetric -> only the 10 upper-triangle
//       128x128 tiles (of 4x4) are computed (-37.5% compute/write).
//   kr: reduce 8 bf16 partials (triangle tiles) -> full bf16 gram via
//       mirror (LDS fp32 64x65 transpose, k1-proven pattern) -> ws[0:4.2M)
//   k3: out = Xb16 . gram^T (both K-contig, async-LDS dbuf, XCD-swizzled) -> d_out

typedef __attribute__((ext_vector_type(8))) short short8;
typedef __attribute__((ext_vector_type(4))) float floatx4;

#define BM 128
#define BN 128
#define BK 32

#define BATCH 8
#define SEQ 4096
#define DIM 512
#define SPLITK 8

__device__ __forceinline__ void async_copy16(const __hip_bfloat16* g, __hip_bfloat16* l) {
  __builtin_amdgcn_global_load_lds((const __attribute__((address_space(1))) void*)g,
                                   (__attribute__((address_space(3))) void*)l, 16, 0, 0);
}

// Upper-triangle tile map: t in [0,10) -> (ti<=tj) of a 4x4 tile grid.
__device__ __forceinline__ void tri_map(int t, int& ti, int& tj) {
  if (t < 4)      { ti = 0; tj = t; }
  else if (t < 7) { ti = 1; tj = t - 3; }
  else if (t < 9) { ti = 2; tj = t - 5; }
  else            { ti = 3; tj = 3; }
}

// ---------------- k1: transpose+cast (Xt) and optional straight cast (Xb16) --
__global__ __launch_bounds__(256) void transpose_cast_kernel(
    const float* __restrict__ X, __hip_bfloat16* __restrict__ Xt,
    __hip_bfloat16* __restrict__ Xb16) {
  __shared__ float tile[64][65];
  const int b = blockIdx.z;
  const int s0 = blockIdx.x * 64;
  const int d0 = blockIdx.y * 64;
  const int tid = threadIdx.x;
  const float* Xb = X + (long)b * SEQ * DIM;
  __hip_bfloat16* Xtb = Xt + (long)b * DIM * SEQ;
  // float4-vectorized tile fill: 4 global loads/thread instead of 16 scalar.
  {
    const int c4 = (tid & 15) * 4;
    const int r0 = tid >> 4;  // 0..15
#pragma unroll
    for (int r = 0; r < 64; r += 16) {
      const float4 v = *(const float4*)&Xb[(long)(s0 + r + r0) * DIM + d0 + c4];
      tile[r + r0][c4 + 0] = v.x;
      tile[r + r0][c4 + 1] = v.y;
      tile[r + r0][c4 + 2] = v.z;
      tile[r + r0][c4 + 3] = v.w;
    }
  }
  __syncthreads();
  // Xt[d][s]: pack 8 consecutive s per 16B store.
#pragma unroll
  for (int it = 0; it < 2; ++it) {
    const int idx = it * 256 + tid;    // 0..511
    const int dl = idx >> 3;           // 0..63
    const int so = (idx & 7) * 8;      // 0,8,..,56
    union { short8 v; __hip_bfloat16 e[8]; } u;
#pragma unroll
    for (int j = 0; j < 8; ++j) u.e[j] = __float2bfloat16(tile[so + j][dl]);
    *(short8*)&Xtb[(long)(d0 + dl) * SEQ + s0 + so] = u.v;
  }
  // Xb16[s][d]: straight cast, pack 8 consecutive d per 16B store.
  if (Xb16 != nullptr) {
    __hip_bfloat16* Xcb = Xb16 + (long)b * SEQ * DIM;
#pragma unroll
    for (int it = 0; it < 2; ++it) {
      const int idx = it * 256 + tid;  // 0..511
      const int sl = idx >> 3;         // 0..63
      const int dc = idx & 7;          // 8-wide d chunk
      union { short8 v; __hip_bfloat16 e[8]; } u;
#pragma unroll
      for (int j = 0; j < 8; ++j) u.e[j] = __float2bfloat16(tile[sl][dc * 8 + j]);
      *(short8*)&Xcb[(long)(s0 + sl) * DIM + d0 + dc * 8] = u.v;
    }
  }
}

// ---------------- GEMM: C = A . Bt^T (Bt stored [N][K], K-contiguous) -------
// Double-buffered LDS: next tile's global_load_lds copies are issued right
// after the barrier that opens compute on the current buffer.
// __launch_bounds__(256,4): force <=128 unified regs/wave -> 4 blocks/CU.
// NSPLIT: split-K factor. AFP32: A fp32 cast-in-staging w/ register prefetch.
// CT: C element type (float or bf16).
// SWZ=1: grid(128,1,B) k3-style: m-slab's 4 n-blocks share an XCD.
// SWZ=2: grid(B*NSPLIT,10,1) k2-style: one (b,split) chunk -> one XCD;
//        blockIdx.y indexes the UPPER-TRIANGLE tile set (gram symmetric).
template <int NSPLIT, bool AFP32, int SWZ, typename CT>
__global__ __launch_bounds__(256, 4) void gemm_bt_kernel(
    const float* __restrict__ Af, const __hip_bfloat16* __restrict__ Ab,
    const __hip_bfloat16* __restrict__ Bt, CT* __restrict__ C,
    int K, int lda, int ldb, int ldc, long strideA, long strideB, long strideC) {
  __shared__ __align__(16) __hip_bfloat16 As[2][BM * BK];  // [m][k]
  __shared__ __align__(16) __hip_bfloat16 Bs[2][BN * BK];  // [n][k]

  int bz, m0, n0;
  if constexpr (SWZ == 1) {
    const int lin = blockIdx.x;        // 0..127 per batch
    bz = blockIdx.z;
    const int xcd = lin & 7;
    const int t = lin >> 3;            // 0..15
    n0 = (t & 3) * BN;
    m0 = ((t >> 2) * 8 + xcd) * BM;
  } else if constexpr (SWZ == 2) {
    bz = blockIdx.x;                   // chunk id, fastest dim -> xcd = bz & 7
    int ti, tj;
    tri_map(blockIdx.y, ti, tj);       // upper triangle only
    m0 = ti * BM;
    n0 = tj * BN;
  } else {
    bz = blockIdx.z;
    m0 = blockIdx.y * BM;
    n0 = blockIdx.x * BN;
  }
  const int b = bz / NSPLIT;
  const int split = bz % NSPLIT;
  const int klen = K / NSPLIT;
  const int kb = split * klen;

  const int tid = threadIdx.x;
  const int w = tid >> 6;
  const int lane = tid & 63;
  const int r16 = lane & 15;
  const int kg = lane >> 4;
  const int wr = w >> 1;
  const int wc = w & 1;

  const float* Afb = AFP32 ? Af + b * strideA : nullptr;
  const __hip_bfloat16* Abb = AFP32 ? nullptr : Ab + b * strideA;
  const __hip_bfloat16* Btb = Bt + b * strideB;
  CT* Cb = C + (long)bz * strideC;

  const floatx4 vzero = {0.f, 0.f, 0.f, 0.f};
  floatx4 acc[4][4];
#pragma unroll
  for (int i = 0; i < 4; ++i)
#pragma unroll
    for (int j = 0; j < 4; ++j) acc[i][j] = vzero;

  const int arow = tid >> 1;
  const int ahalf = tid & 1;
  float f[16];

  auto stageB = [&](int buf, int k0) {
#pragma unroll
    for (int q = 0; q < 2; ++q) {
      const __hip_bfloat16* gb =
          Btb + (long)(n0 + w * 32 + q * 16 + (lane >> 2)) * ldb + k0 + (lane & 3) * 8;
      async_copy16(gb, &Bs[buf][(w * 32 + q * 16) * BK]);
    }
  };
  auto stageA = [&](int buf, int k0) {
#pragma unroll
    for (int q = 0; q < 2; ++q) {
      const __hip_bfloat16* ga =
          Abb + (long)(m0 + w * 32 + q * 16 + (lane >> 2)) * lda + k0 + (lane & 3) * 8;
      async_copy16(ga, &As[buf][(w * 32 + q * 16) * BK]);
    }
  };
  auto loadF = [&](int k0) {
    const float* ar = Afb + (long)(m0 + arow) * lda + k0 + ahalf * 16;
    *(float4*)(f + 0)  = *(const float4*)(ar + 0);
    *(float4*)(f + 4)  = *(const float4*)(ar + 4);
    *(float4*)(f + 8)  = *(const float4*)(ar + 8);
    *(float4*)(f + 12) = *(const float4*)(ar + 12);
  };
  auto writeF = [&](int buf) {
    union { short8 v[2]; __hip_bfloat16 e[16]; } u;
#pragma unroll
    for (int t = 0; t < 16; ++t) u.e[t] = __float2bfloat16(f[t]);
    short8* dst = (short8*)&As[buf][arow * BK + ahalf * 16];
    dst[0] = u.v[0];
    dst[1] = u.v[1];
  };

  const int nIter = klen / BK;
  // prologue: fill buffer 0
  if constexpr (AFP32) {
    loadF(kb);
    writeF(0);
    loadF(kb + BK);  // prefetch tile 1 into registers
  } else {
    stageA(0, kb);
  }
  stageB(0, kb);

  for (int t = 0; t < nIter; ++t) {
    const int cur = t & 1;
    __syncthreads();  // drains vmcnt/lgkm: buffer `cur` is ready
    // issue next tile into the other buffer; it stays in flight during compute
    if (t + 1 < nIter) {
      if constexpr (AFP32) {
        writeF(cur ^ 1);
        if (t + 2 < nIter) loadF(kb + (t + 2) * BK);
      } else {
        stageA(cur ^ 1, kb + (t + 1) * BK);
      }
      stageB(cur ^ 1, kb + (t + 1) * BK);
    }

    short8 a[4], bfrag[4];
#pragma unroll
    for (int i = 0; i < 4; ++i)
      a[i] = *(const short8*)&As[cur][(wr * 64 + i * 16 + r16) * BK + kg * 8];
#pragma unroll
    for (int j = 0; j < 4; ++j)
      bfrag[j] = *(const short8*)&Bs[cur][(wc * 64 + j * 16 + r16) * BK + kg * 8];
#pragma unroll
    for (int i = 0; i < 4; ++i)
#pragma unroll
      for (int j = 0; j < 4; ++j)
        acc[i][j] = __builtin_amdgcn_mfma_f32_16x16x32_bf16(a[i], bfrag[j], acc[i][j], 0, 0, 0);
  }

  // epilogue: row = kg*4 + r, col = r16 (m89-verified C/D map)
#pragma unroll
  for (int i = 0; i < 4; ++i) {
    const int row_base = m0 + wr * 64 + i * 16 + kg * 4;
#pragma unroll
    for (int j = 0; j < 4; ++j) {
      const int col = n0 + wc * 64 + j * 16 + r16;
#pragma unroll
      for (int r = 0; r < 4; ++r) {
        const float v = acc[i][j][r];
        if constexpr (std::is_same<CT, float>::value)
          Cb[(long)(row_base + r) * ldc + col] = v;
        else
          Cb[(long)(row_base + r) * ldc + col] = __float2bfloat16(v);
      }
    }
  }
}

// ---------------- kr: reduce NSPLIT partials (triangle) -> full gram --------
// grid (10, BATCH). Each block: one upper-triangle 128x128 tile (ti,tj).
// Sums 8 bf16 partials in fp32, stores straight to gram[ti,tj]; for ti!=tj
// also stores the mirror gram[tj,ti] via an fp32 64x65 LDS transpose
// (k1-proven bank-clean pattern), one 64x64 quadrant at a time.
template <int NSPLIT>
__global__ __launch_bounds__(256) void reduce_mirror_kernel(
    const __hip_bfloat16* __restrict__ P, __hip_bfloat16* __restrict__ G) {
  __shared__ float tile[64][65];
  int ti, tj;
  tri_map(blockIdx.x, ti, tj);
  const int b = blockIdx.y;
  const __hip_bfloat16* Pb = P + (long)b * NSPLIT * DIM * DIM;
  __hip_bfloat16* Gb = G + (long)b * DIM * DIM;
  const int r0 = ti * 128, c0 = tj * 128;
  const int tid = threadIdx.x;
  const int lrow = tid >> 3;        // 0..31
  const int lcol = (tid & 7) * 8;   // 0..56

#pragma unroll
  for (int q = 0; q < 4; ++q) {
    const int qr = (q >> 1) * 64, qc = (q & 1) * 64;
    float s[2][8];
#pragma unroll
    for (int h = 0; h < 2; ++h) {
      const int row = lrow + h * 32;
#pragma unroll
      for (int j = 0; j < 8; ++j) s[h][j] = 0.f;
#pragma unroll
      for (int p = 0; p < NSPLIT; ++p) {
        union { short8 v; __hip_bfloat16 e8[8]; } u;
        u.v = *(const short8*)&Pb[(long)p * DIM * DIM +
                                  (long)(r0 + qr + row) * DIM + c0 + qc + lcol];
#pragma unroll
        for (int j = 0; j < 8; ++j) s[h][j] += __bfloat162float(u.e8[j]);
      }
      union { short8 v; __hip_bfloat16 e8[8]; } o;
#pragma unroll
      for (int j = 0; j < 8; ++j) o.e8[j] = __float2bfloat16(s[h][j]);
      *(short8*)&Gb[(long)(r0 + qr + row) * DIM + c0 + qc + lcol] = o.v;
    }
    if (ti != tj) {
      if (q) __syncthreads();  // previous quadrant's transposed reads done
#pragma unroll
      for (int h = 0; h < 2; ++h) {
        const int row = lrow + h * 32;
#pragma unroll
        for (int j = 0; j < 8; ++j) tile[row][lcol + j] = s[h][j];
      }
      __syncthreads();
#pragma unroll
      for (int it = 0; it < 2; ++it) {
        const int idx = it * 256 + tid;   // 0..511
        const int dl = idx >> 3;          // 0..63  (mirror-tile local row)
        const int so = (idx & 7) * 8;     // 0,8,..,56 (mirror-tile col chunk)
        union { short8 v; __hip_bfloat16 e8[8]; } o;
#pragma unroll
        for (int j = 0; j < 8; ++j) o.e8[j] = __float2bfloat16(tile[so + j][dl]);
        *(short8*)&Gb[(long)(c0 + qc + dl) * DIM + r0 + qr + so] = o.v;
      }
    }
  }
}

// ---------------- host launch ----------------------------------------------
extern "C" void kernel_launch(void* const* d_in, const int* in_sizes, int n_in,
                              void* d_out, int out_size, void* d_ws, size_t ws_size,
                              hipStream_t stream) {
  const float* X = (const float*)d_in[0];
  float* out = (float*)d_out;
  const long xtBytes = (long)BATCH * DIM * SEQ * 2;               // 33.5 MB
  const long gramBytes = (long)BATCH * DIM * DIM * 2;             // 4.2 MB
  const long partBytes = (long)BATCH * SPLITK * DIM * DIM * 2;    // 33.5 MB (bf16)
  __hip_bfloat16* Xt = (__hip_bfloat16*)d_out;
  __hip_bfloat16* gram = (__hip_bfloat16*)d_ws;

  const bool bigWs = ws_size >= (size_t)(gramBytes + xtBytes + partBytes);
  const bool midWs = ws_size >= (size_t)(gramBytes + xtBytes);
  __hip_bfloat16* Xb16 = midWs ? (__hip_bfloat16*)((char*)d_ws + gramBytes) : nullptr;

  // k1: Xt[b][d][s] (+ Xb16[b][s][d] if ws fits)
  transpose_cast_kernel<<<dim3(SEQ / 64, DIM / 64, BATCH), 256, 0, stream>>>(X, Xt, Xb16);

  // k2: split-8 gram partials (bf16), upper-triangle tiles only (symmetry),
  // XCD-swizzled, double-buffered. grid = 64 chunks x 10 tiles = 640 blocks.
  __hip_bfloat16* partials = bigWs
      ? (__hip_bfloat16*)((char*)d_ws + gramBytes + xtBytes)
      : (__hip_bfloat16*)((char*)d_out + xtBytes);
  gemm_bt_kernel<SPLITK, false, 2, __hip_bfloat16>
      <<<dim3(BATCH * SPLITK, 10, 1), 256, 0, stream>>>(
          nullptr, Xt, Xt, partials, SEQ, SEQ, SEQ, DIM,
          (long)DIM * SEQ, (long)DIM * SEQ, (long)DIM * DIM);

  // kr: triangle partials -> full gram (mirror off-diagonal tiles)
  reduce_mirror_kernel<SPLITK><<<dim3(10, BATCH), 256, 0, stream>>>(partials, gram);

  // k3: out = A . gram^T (M=4096, N=512, K=512), XCD-swizzled, double-buffered
  if (midWs) {
    gemm_bt_kernel<1, false, 1, float><<<dim3(128, 1, BATCH), 256, 0, stream>>>(
        nullptr, Xb16, gram, out, DIM, DIM, DIM, DIM,
        (long)SEQ * DIM, (long)DIM * DIM, (long)SEQ * DIM);
  } else {
    gemm_bt_kernel<1, true, 1, float><<<dim3(128, 1, BATCH), 256, 0, stream>>>(
        X, nullptr, gram, out, DIM, DIM, DIM, DIM,
        (long)SEQ * DIM, (long)DIM * DIM, (long)SEQ * DIM);
  }
}